// Round 2
// baseline (89.643 us; speedup 1.0000x reference)
//
#include <hip/hip_runtime.h>
#include <hip/hip_bf16.h>
#include <math.h>

#define B_   4
#define T1_  4096
#define T2_  512
#define IC_  32
#define OC_  64
#define KS_  64

typedef unsigned short u16;
typedef unsigned int   u32;

__device__ __forceinline__ float bf2f(u16 h) {
    union { u32 u; float f; } v; v.u = ((u32)h) << 16; return v.f;
}
__device__ __forceinline__ u16 f2bf(float f) {
    union { u32 u; float f; } v; v.f = f;
    u32 u = v.u;
    u32 r = (u + 0x7FFFu + ((u >> 16) & 1u)) >> 16;   // round-to-nearest-even
    return (u16)r;
}

#define PI_F 3.14159265358979323846f

// ---------------------------------------------------------------------------
// prep: repack kernel (o,c,s) fp32 -> KT[cs4][o][4] fp32 (cs = c*64+s)
// so gemm's per-lane-o reads of 4 consecutive cs are coalesced across lanes.
// ---------------------------------------------------------------------------
__global__ __launch_bounds__(256) void prep_kernel(const float* __restrict__ kern,
                                                   float* __restrict__ KT)
{
    int gid = blockIdx.x * 256 + threadIdx.x;   // 0..32767
    int o   = gid >> 9;                          // 0..63
    int cs4 = gid & 511;                         // 0..511
    // kernel flat layout: ((o*IC_ + c)*64 + s) == o*2048 + cs  (cs = c*64+s)
    float4 v = *(const float4*)(kern + (size_t)o * 2048 + (cs4 << 2));
    *(float4*)(KT + ((size_t)cs4 * 64 + o) * 4) = v;
}

// ---------------------------------------------------------------------------
// interp: per (b,t2) block. Builds fractional-delay filter w[64] (closed form
// of irfft(phase shift), incl. Nyquist cos(pi f) term) and the 64x32 x-window;
// computes y[s][c] = sum_j w[j]*xwin[(s+j)&63][c]; writes Y[bt][c][s] bf16.
// ---------------------------------------------------------------------------
__global__ __launch_bounds__(256) void interp_kernel(const float* __restrict__ x,
                                                     const float* __restrict__ index,
                                                     u16* __restrict__ Y)
{
    __shared__ __align__(16) float xwT[IC_][68];   // [c][k], pad 68 for banks
    __shared__ float wsh[64];

    const int bt  = blockIdx.x;
    const int b   = bt >> 9;        // T2_ = 512
    const int tid = threadIdx.x;

    float fidx = index[bt];
    float flo  = floorf(fidx);
    int   i0   = (int)flo;
    float f    = fidx - flo;

    // ---- load x window (zero-padded) into LDS, transposed to [c][k] ----
    {
        int e  = tid * 8;          // flat over (k,c): e = k*32 + c0
        int k  = e >> 5;           // 0..63
        int c0 = e & 31;           // multiple of 8
        int pos = i0 + k - 32;     // position in x time axis
        float vals[8];
        if (pos >= 0 && pos < T1_) {
            const float* p = x + ((size_t)(b * T1_ + pos) * IC_ + c0);
            float4 a = *(const float4*)p;
            float4 d = *(const float4*)(p + 4);
            vals[0]=a.x; vals[1]=a.y; vals[2]=a.z; vals[3]=a.w;
            vals[4]=d.x; vals[5]=d.y; vals[6]=d.z; vals[7]=d.w;
        } else {
            #pragma unroll
            for (int q = 0; q < 8; ++q) vals[q] = 0.0f;
        }
        #pragma unroll
        for (int q = 0; q < 8; ++q) xwT[c0 + q][k] = vals[q];
    }

    // ---- w[j] = D(j+f), D(u) = sin(pi u) cos(pi u/64) / (64 sin(pi u/64)) ----
    if (tid < 64) {
        int j = tid;
        float wj;
        if (f <= 0.0f) {
            wj = (j == 0) ? 1.0f : 0.0f;
        } else {
            float spf = sinf(PI_F * f);          // sin(pi(j+f)) = (-1)^j sin(pi f)
            float a   = PI_F * ((float)j + f) * (1.0f / 64.0f);
            float sa  = sinf(a);
            float ca  = cosf(a);
            wj = ((j & 1) ? -spf : spf) * ca / (64.0f * sa);
        }
        wsh[j] = wj;
    }
    __syncthreads();

    // ---- thread owns (c, s0..s0+7); rotated register window ----
    const int c  = tid >> 3;           // 0..31
    const int s0 = (tid & 7) << 3;     // 0..56 step 8

    float xr[64];
    #pragma unroll
    for (int q = 0; q < 16; ++q) {
        int idx = (s0 + q * 4) & 63;   // 4-aligned, wraps at 64
        const float4 v = *(const float4*)&xwT[c][idx];
        xr[q*4+0] = v.x; xr[q*4+1] = v.y; xr[q*4+2] = v.z; xr[q*4+3] = v.w;
    }

    float acc[8];
    #pragma unroll
    for (int r = 0; r < 8; ++r) acc[r] = 0.0f;

    #pragma unroll
    for (int j = 0; j < 64; ++j) {
        float wj = wsh[j];             // wave-uniform broadcast read
        #pragma unroll
        for (int r = 0; r < 8; ++r)
            acc[r] += wj * xr[(j + r) & 63];   // static index after unroll
    }

    // ---- write Y[bt][c][s0..s0+7] bf16 (16B per thread, coalesced) ----
    u16 ov[8];
    #pragma unroll
    for (int r = 0; r < 8; ++r) ov[r] = f2bf(acc[r]);
    u16* yp = Y + ((size_t)bt * 2048 + c * 64 + s0);
    *(ushort4*)(yp)     = make_ushort4(ov[0], ov[1], ov[2], ov[3]);
    *(ushort4*)(yp + 4) = make_ushort4(ov[4], ov[5], ov[6], ov[7]);
}

// ---------------------------------------------------------------------------
// gemm: out[bt,o] = bias[o] + sum_cs Y[bt,cs] * kernel[o,cs]
// block = 4 bt rows x 64 o-lanes x 4 K-chunks; LDS reduction; fp32 out.
// ---------------------------------------------------------------------------
__global__ __launch_bounds__(256) void gemm_kernel(const u16* __restrict__ Y,
                                                   const float* __restrict__ KT,
                                                   const float* __restrict__ bias,
                                                   float* __restrict__ out)
{
    __shared__ __align__(16) float Ylds[4][2048];
    __shared__ float red[4][4][64];       // [kq][row][o]

    const int tid = threadIdx.x;
    const int bt0 = blockIdx.x * 4;

    // ---- stage 4 rows of Y (bf16 -> fp32) into LDS ----
    #pragma unroll
    for (int it = 0; it < 4; ++it) {
        int e   = (it * 256 + tid) * 8;   // 0..8191
        int row = e >> 11;
        int col = e & 2047;
        const u16* p = Y + ((size_t)(bt0 + row) * 2048 + col);
        ushort4 a = *(const ushort4*)p;
        ushort4 d = *(const ushort4*)(p + 4);
        Ylds[row][col+0]=bf2f(a.x); Ylds[row][col+1]=bf2f(a.y);
        Ylds[row][col+2]=bf2f(a.z); Ylds[row][col+3]=bf2f(a.w);
        Ylds[row][col+4]=bf2f(d.x); Ylds[row][col+5]=bf2f(d.y);
        Ylds[row][col+6]=bf2f(d.z); Ylds[row][col+7]=bf2f(d.w);
    }
    __syncthreads();

    const int o  = tid & 63;
    const int kq = tid >> 6;              // 0..3, K-chunk of 128 cs4 groups

    float acc0 = 0.f, acc1 = 0.f, acc2 = 0.f, acc3 = 0.f;

    for (int i2 = 0; i2 < 128; ++i2) {
        int cs4 = kq * 128 + i2;
        float4 kv = *(const float4*)(KT + ((size_t)cs4 * 64 + o) * 4);
        int cc = cs4 * 4;
        float4 y0 = *(const float4*)&Ylds[0][cc];
        float4 y1 = *(const float4*)&Ylds[1][cc];
        float4 y2 = *(const float4*)&Ylds[2][cc];
        float4 y3 = *(const float4*)&Ylds[3][cc];
        acc0 += kv.x*y0.x + kv.y*y0.y + kv.z*y0.z + kv.w*y0.w;
        acc1 += kv.x*y1.x + kv.y*y1.y + kv.z*y1.z + kv.w*y1.w;
        acc2 += kv.x*y2.x + kv.y*y2.y + kv.z*y2.z + kv.w*y2.w;
        acc3 += kv.x*y3.x + kv.y*y3.y + kv.z*y3.z + kv.w*y3.w;
    }

    red[kq][0][o] = acc0;
    red[kq][1][o] = acc1;
    red[kq][2][o] = acc2;
    red[kq][3][o] = acc3;
    __syncthreads();

    {
        int r  = tid >> 6;
        int oo = tid & 63;
        float s = red[0][r][oo] + red[1][r][oo] + red[2][r][oo] + red[3][r][oo]
                + bias[oo];
        out[(size_t)(bt0 + r) * 64 + oo] = s;
    }
}

// ---------------------------------------------------------------------------
extern "C" void kernel_launch(void* const* d_in, const int* in_sizes, int n_in,
                              void* d_out, int out_size, void* d_ws, size_t ws_size,
                              hipStream_t stream)
{
    const float* x     = (const float*)d_in[0];   // (4,4096,32) fp32
    const float* index = (const float*)d_in[1];   // (4,512) fp32
    const float* kern  = (const float*)d_in[2];   // (64,32,64) fp32
    const float* bias  = (const float*)d_in[3];   // (64,) fp32
    float* out = (float*)d_out;                   // (4,512,64) fp32

    u16*   Y  = (u16*)d_ws;                                       // 2048*2048 bf16 = 8 MB
    float* KT = (float*)((char*)d_ws + (size_t)8 * 1024 * 1024);  // 512 KB

    prep_kernel<<<dim3(128), dim3(256), 0, stream>>>(kern, KT);
    interp_kernel<<<dim3(B_ * T2_), dim3(256), 0, stream>>>(x, index, Y);
    gemm_kernel<<<dim3(B_ * T2_ / 4), dim3(256), 0, stream>>>(Y, KT, bias, out);
}